// Round 16
// baseline (137.902 us; speedup 1.0000x reference)
//
#include <hip/hip_runtime.h>

#define DIM 64
#define NPB 256          // nodes per bucket (bucket id = dst >> 8)
#define MAXBUCK 512      // N up to 131072
#define CHUNK 4096       // edges per binning block

__device__ __forceinline__ unsigned short f2bf(float v) {
    unsigned u = __float_as_uint(v);
    unsigned r = (u + 0x7fffu + ((u >> 16) & 1u)) >> 16;  // RNE
    return (unsigned short)r;
}

// h = x @ W -> bf16. Thread = 4 nodes x 4 dims; per k: 2x ds_read_b128 + 16 FMA.
// xsT transposed [k][node] (pad 68: 16B-aligned rows, conflict-free b128 reads).
// unroll capped (R14: full unroll -> VGPR spill -> 1 GB scratch traffic).
__global__ void gcn_matmul(const float* __restrict__ x, const float* __restrict__ W,
                           unsigned short* __restrict__ hbf, int N) {
    __shared__ float Wl[DIM * DIM];    // 16 KB row-major [k][d]
    __shared__ float xsT[DIM][68];     // 17 KB transposed x tile [k][node]
    int tid = threadIdx.x;
    for (int i = tid; i < 1024; i += 256)
        ((float4*)Wl)[i] = ((const float4*)W)[i];
    int node0 = blockIdx.x * 64;
#pragma unroll
    for (int rep = 0; rep < 4; ++rep) {
        int i = rep * 256 + tid;       // 0..1023
        int nn = i >> 4;               // node-in-block 0..63
        int c4 = (i & 15) * 4;         // feature base
        int gn = node0 + nn;
        float4 v;
        if (gn < N) v = *(const float4*)(x + (long)gn * DIM + c4);
        else { v.x = v.y = v.z = v.w = 0.f; }
        xsT[c4 + 0][nn] = v.x;
        xsT[c4 + 1][nn] = v.y;
        xsT[c4 + 2][nn] = v.z;
        xsT[c4 + 3][nn] = v.w;
    }
    __syncthreads();

    int lane = tid & 63, wv_ = tid >> 6;
    int d4 = (lane & 15) * 4;          // dim base
    int n0 = wv_ * 16 + (lane >> 4) * 4;  // node base (4 nodes)
    float4 a0, a1, a2, a3;
    a0.x = a0.y = a0.z = a0.w = 0.f;
    a1.x = a1.y = a1.z = a1.w = 0.f;
    a2.x = a2.y = a2.z = a2.w = 0.f;
    a3.x = a3.y = a3.z = a3.w = 0.f;
#pragma unroll 2
    for (int k = 0; k < DIM; ++k) {
        float4 wr = *(const float4*)&Wl[k * DIM + d4];
        float4 xv = *(const float4*)&xsT[k][n0];
        a0.x += xv.x * wr.x; a0.y += xv.x * wr.y; a0.z += xv.x * wr.z; a0.w += xv.x * wr.w;
        a1.x += xv.y * wr.x; a1.y += xv.y * wr.y; a1.z += xv.y * wr.z; a1.w += xv.y * wr.w;
        a2.x += xv.z * wr.x; a2.y += xv.z * wr.y; a2.z += xv.z * wr.z; a2.w += xv.z * wr.w;
        a3.x += xv.w * wr.x; a3.y += xv.w * wr.y; a3.z += xv.w * wr.z; a3.w += xv.w * wr.w;
    }
#define STORE_NODE(j, aj)                                                   \
    {                                                                       \
        int gn = node0 + n0 + j;                                            \
        if (gn < N) {                                                       \
            uint2 p;                                                       \
            p.x = (unsigned)f2bf(aj.x) | ((unsigned)f2bf(aj.y) << 16);      \
            p.y = (unsigned)f2bf(aj.z) | ((unsigned)f2bf(aj.w) << 16);      \
            *(uint2*)(hbf + (long)gn * DIM + d4) = p;                       \
        }                                                                   \
    }
    STORE_NODE(0, a0) STORE_NODE(1, a1) STORE_NODE(2, a2) STORE_NODE(3, a3)
#undef STORE_NODE
}

__global__ void zero_i32(int* __restrict__ p, int n) {
    int i = blockIdx.x * 256 + threadIdx.x;
    if (i < n) p[i] = 0;
}

// bucket histogram only (LDS-aggregated)
__global__ void count_buckets(const int* __restrict__ ei, int* __restrict__ bcount,
                              int E, int nbuck) {
    __shared__ int hist[MAXBUCK];
    int tid = threadIdx.x;
    for (int i = tid; i < nbuck; i += 256) hist[i] = 0;
    __syncthreads();
    for (long e = (long)blockIdx.x * 256 + tid; e < E; e += (long)gridDim.x * 256)
        atomicAdd(&hist[ei[E + e] >> 8], 1);
    __syncthreads();
    for (int i = tid; i < nbuck; i += 256)
        if (hist[i]) atomicAdd(&bcount[i], hist[i]);
}

// single-block exclusive scan of bucket counts -> boff, init bcur
__global__ void scan_buckets(const int* __restrict__ bcount, int* __restrict__ boff,
                             int* __restrict__ bcur, int nbuck, int E) {
    __shared__ int sh[MAXBUCK];
    int tid = threadIdx.x;  // 512
    int v = (tid < nbuck) ? bcount[tid] : 0;
    sh[tid] = v;
    __syncthreads();
    for (int d = 1; d < MAXBUCK; d <<= 1) {
        int t = (tid >= d) ? sh[tid - d] : 0;
        __syncthreads();
        sh[tid] += t;
        __syncthreads();
    }
    if (tid < nbuck) {
        int o = sh[tid] - v;
        boff[tid] = o;
        bcur[tid] = o;
    }
    if (tid == 0) boff[nbuck] = E;
}

// phase A: bin edges into bucket-contiguous storage; entry = (src<<8) | (dst&255)
__global__ void bin_edges(const int* __restrict__ ei, int* __restrict__ bcur,
                          unsigned* __restrict__ binned, int E, int nbuck) {
    __shared__ int hist[MAXBUCK];
    int tid = threadIdx.x;
    long e0 = (long)blockIdx.x * CHUNK;
    for (int i = tid; i < nbuck; i += 256) hist[i] = 0;
    __syncthreads();
    int s[16], t[16];
#pragma unroll
    for (int it = 0; it < 16; ++it) {
        long e = e0 + it * 256 + tid;
        if (e < E) {
            s[it] = ei[e];
            t[it] = ei[E + e];
            atomicAdd(&hist[t[it] >> 8], 1);
        } else {
            s[it] = -1;
        }
    }
    __syncthreads();
    for (int i = tid; i < nbuck; i += 256) {
        int c = hist[i];
        hist[i] = c ? atomicAdd(&bcur[i], c) : 0;
    }
    __syncthreads();
#pragma unroll
    for (int it = 0; it < 16; ++it) {
        if (s[it] >= 0) {
            int b = t[it] >> 8;
            int p = atomicAdd(&hist[b], 1);
            binned[p] = ((unsigned)s[it] << 8) | (unsigned)(t[it] & 255);
        }
    }
}

// phase B: per-bucket LDS counting sort -> per-node CSR (adj, rowptr off, dinv)
__global__ void bucket_sort(const int* __restrict__ boff, const unsigned* __restrict__ binned,
                            int* __restrict__ off, int* __restrict__ adj,
                            float* __restrict__ dinv, int N, int E) {
    __shared__ int lcur[NPB];
    __shared__ int sh[NPB];
    int bid = blockIdx.x, tid = threadIdx.x;  // 256 threads
    int node0 = bid << 8;
    int e0 = boff[bid], e1 = boff[bid + 1];
    lcur[tid] = 0;
    __syncthreads();
    for (int e = e0 + tid; e < e1; e += 256)
        atomicAdd(&lcur[binned[e] & 255], 1);
    __syncthreads();
    int v = lcur[tid];
    sh[tid] = v;
    __syncthreads();
    for (int d = 1; d < NPB; d <<= 1) {
        int t = (tid >= d) ? sh[tid - d] : 0;
        __syncthreads();
        sh[tid] += t;
        __syncthreads();
    }
    int excl = sh[tid] - v;
    __syncthreads();
    lcur[tid] = excl;
    int node = node0 + tid;
    if (node < N) {
        off[node] = e0 + excl;
        dinv[node] = rsqrtf((float)v + 1.0f);
    }
    if (tid == 0 && bid == gridDim.x - 1) off[N] = E;
    __syncthreads();
    for (int e = e0 + tid; e < e1; e += 256) {
        unsigned u = binned[e];
        int p = atomicAdd(&lcur[u & 255], 1);
        adj[e0 + p] = (int)(u >> 8);
    }
}

// one wave per node; 4 edges per load (uint2 = 4 bf16 feats, 16 lanes/row).
// lane = sub (edge slot, lane>>4) x f2 (uint2 index, lane&15).
__global__ void gather_agg(const int* __restrict__ off, const int* __restrict__ adj,
                           const uint2* __restrict__ hb2, const float* __restrict__ dinv,
                           const float4* __restrict__ x4, const float4* __restrict__ b4,
                           float4* __restrict__ o4, int N) {
    int node = blockIdx.x * 4 + (threadIdx.x >> 6);
    int lane = threadIdx.x & 63;
    if (node >= N) return;
    int sub = lane >> 4;     // edge slot 0..3
    int f2 = lane & 15;      // uint2 (4 features) index
    int start = off[node];
    int m = off[node + 1] - start;
    float dn = dinv[node];
    float a0 = 0.f, a1 = 0.f, a2 = 0.f, a3 = 0.f;

    for (int c = 0; c < m; c += 64) {
        int rem = m - c;
        int take = rem < 64 ? rem : 64;
        int s = (lane < take) ? adj[start + c + lane] : 0;
        float w = (lane < take) ? dinv[s] : 0.f;
        for (int i = 0; i < take; i += 16) {
#define GRP(j)                                                        \
            if (i + 4 * j < take) {                                   \
                int idx = i + 4 * j + sub;                            \
                int ts = __shfl(s, idx);                              \
                float tw = __shfl(w, idx);                            \
                uint2 u = hb2[(long)ts * 16 + f2];                    \
                a0 += __uint_as_float(u.x << 16) * tw;                \
                a1 += __uint_as_float(u.x & 0xffff0000u) * tw;        \
                a2 += __uint_as_float(u.y << 16) * tw;                \
                a3 += __uint_as_float(u.y & 0xffff0000u) * tw;        \
            }
            GRP(0) GRP(1) GRP(2) GRP(3)
#undef GRP
        }
    }
    // merge the 4 edge-slot partial sums
    a0 += __shfl_xor(a0, 16); a1 += __shfl_xor(a1, 16);
    a2 += __shfl_xor(a2, 16); a3 += __shfl_xor(a3, 16);
    a0 += __shfl_xor(a0, 32); a1 += __shfl_xor(a1, 32);
    a2 += __shfl_xor(a2, 32); a3 += __shfl_xor(a3, 32);
    // self loop (post-merge)
    uint2 us = hb2[(long)node * 16 + f2];
    a0 += __uint_as_float(us.x << 16) * dn;
    a1 += __uint_as_float(us.x & 0xffff0000u) * dn;
    a2 += __uint_as_float(us.y << 16) * dn;
    a3 += __uint_as_float(us.y & 0xffff0000u) * dn;

    if (sub == 0) {
        long gi = (long)node * 16 + f2;
        float4 bb = b4[f2];
        float4 xx = x4[gi];
        float4 r;
        r.x = xx.x + fmaxf(a0 * dn + bb.x, 0.f);
        r.y = xx.y + fmaxf(a1 * dn + bb.y, 0.f);
        r.z = xx.z + fmaxf(a2 * dn + bb.z, 0.f);
        r.w = xx.w + fmaxf(a3 * dn + bb.w, 0.f);
        o4[gi] = r;
    }
}

extern "C" void kernel_launch(void* const* d_in, const int* in_sizes, int n_in,
                              void* d_out, int out_size, void* d_ws, size_t ws_size,
                              hipStream_t stream) {
    const float* x = (const float*)d_in[0];
    const int* ei  = (const int*)d_in[1];
    const float* W = (const float*)d_in[2];
    const float* b = (const float*)d_in[3];
    float* out = (float*)d_out;

    int N = in_sizes[0] / DIM;
    int E = in_sizes[1] / 2;
    int nbuck = (N + NPB - 1) / NPB;  // 391

    char* ws = (char*)d_ws;
    size_t o = 0;
    unsigned short* hbf = (unsigned short*)(ws + o); o += (size_t)N * DIM * sizeof(unsigned short);
    float* dinv  = (float*)(ws + o); o += (size_t)N * sizeof(float);
    int*   off   = (int*)(ws + o);   o += (size_t)(N + 1) * sizeof(int);
    int*   bcount= (int*)(ws + o);   o += (size_t)nbuck * sizeof(int);
    int*   boff  = (int*)(ws + o);   o += (size_t)(nbuck + 1) * sizeof(int);
    int*   bcur  = (int*)(ws + o);   o += (size_t)nbuck * sizeof(int);
    unsigned* binned = (unsigned*)(ws + o); o += (size_t)E * sizeof(unsigned);
    int*   adj   = (int*)(ws + o);   o += (size_t)E * sizeof(int);

    gcn_matmul<<<(N + 63) / 64, 256, 0, stream>>>(x, W, hbf, N);
    zero_i32<<<(nbuck + 255) / 256, 256, 0, stream>>>(bcount, nbuck);
    count_buckets<<<512, 256, 0, stream>>>(ei, bcount, E, nbuck);
    scan_buckets<<<1, MAXBUCK, 0, stream>>>(bcount, boff, bcur, nbuck, E);
    bin_edges<<<(E + CHUNK - 1) / CHUNK, 256, 0, stream>>>(ei, bcur, binned, E, nbuck);
    bucket_sort<<<nbuck, 256, 0, stream>>>(boff, binned, off, adj, dinv, N, E);
    gather_agg<<<(N + 3) / 4, 256, 0, stream>>>(off, adj, (const uint2*)hbf, dinv,
                                                (const float4*)x, (const float4*)b,
                                                (float4*)out, N);
}